// Round 4
// baseline (2816.879 us; speedup 1.0000x reference)
//
#include <hip/hip_runtime.h>
#include <cstdint>
#include <cstddef>

typedef __attribute__((ext_vector_type(8))) short  s16x8;
typedef __attribute__((ext_vector_type(4))) short  s16x4;
typedef __attribute__((ext_vector_type(4))) float  f32x4;

#define D_MODEL 2240
#define MOD6    13440
#define NHEAD   70
#define HD      32
#define NIMG    1024
#define NTXT    300
#define DFF_    5600

__device__ __forceinline__ float b2f(short s) {
    union { unsigned int u; float f; } c;
    c.u = ((unsigned int)(unsigned short)s) << 16;
    return c.f;
}
__device__ __forceinline__ short f2b(float f) {
    union { float f; unsigned int u; } c; c.f = f;
    unsigned int r = c.u + 0x7fffu + ((c.u >> 16) & 1u);
    return (short)(r >> 16);
}

// ---------------- timestep embedding + modulation table ----------------
__global__ __launch_bounds__(256)
void tmod_kernel(const int* __restrict__ tstep, const float* __restrict__ Wt,
                 const float* __restrict__ bt, const float* __restrict__ sst,
                 float* __restrict__ mod)
{
    __shared__ float sT[256];
    const int b = blockIdx.y;
    const int tid = threadIdx.x;
    const float tv = (float)tstep[b];
    {
        const float NL = -logf(10000.0f);
        int c = tid & 127;
        float f = expf(NL * ((float)c * (1.0f / 128.0f)));
        float a = tv * f;
        sT[tid] = (tid < 128) ? cosf(a) : sinf(a);
    }
    __syncthreads();
    int j = blockIdx.x * 256 + tid;
    if (j < MOD6) {
        float s = 0.f;
        #pragma unroll 8
        for (int c = 0; c < 256; c++) s += sT[c] * Wt[c * MOD6 + j];
        mod[b * MOD6 + j] = s + bt[j] + sst[j];
    }
}

// ---------------- LayerNorm (no affine) * (1+sc) + sh  -> bf16 ----------------
__global__ __launch_bounds__(256)
void ln_mod_kernel(const float* __restrict__ x, const float* __restrict__ mod,
                   unsigned short* __restrict__ out, int scIdx, int shIdx)
{
    const int row = blockIdx.x;          // 0..2047
    const int b = row >> 10;
    const int tid = threadIdx.x;
    const float* xr = x + (size_t)row * D_MODEL;
    const float4 v0 = *reinterpret_cast<const float4*>(xr + (size_t)tid * 4);
    const float4 v1 = *reinterpret_cast<const float4*>(xr + (size_t)(tid + 256) * 4);
    float4 v2 = make_float4(0.f, 0.f, 0.f, 0.f);
    if (tid < 48) v2 = *reinterpret_cast<const float4*>(xr + (size_t)(tid + 512) * 4);
    float s  = v0.x + v0.y + v0.z + v0.w + v1.x + v1.y + v1.z + v1.w
             + v2.x + v2.y + v2.z + v2.w;
    float sq = v0.x*v0.x + v0.y*v0.y + v0.z*v0.z + v0.w*v0.w
             + v1.x*v1.x + v1.y*v1.y + v1.z*v1.z + v1.w*v1.w
             + v2.x*v2.x + v2.y*v2.y + v2.z*v2.z + v2.w*v2.w;
    #pragma unroll
    for (int off = 32; off > 0; off >>= 1) {
        s  += __shfl_down(s, off);
        sq += __shfl_down(sq, off);
    }
    __shared__ float red[8];
    if ((tid & 63) == 0) { red[tid >> 6] = s; red[(tid >> 6) + 4] = sq; }
    __syncthreads();
    s  = red[0] + red[1] + red[2] + red[3];
    sq = red[4] + red[5] + red[6] + red[7];
    const float inv = 1.0f / (float)D_MODEL;
    const float mean = s * inv;
    const float var = sq * inv - mean * mean;
    const float rs = rsqrtf(var + 1e-6f);
    const float* scp = mod + b * MOD6 + scIdx * D_MODEL;
    const float* shp = mod + b * MOD6 + shIdx * D_MODEL;
    unsigned short* orow = out + (size_t)row * D_MODEL;
    auto emit = [&](const float4& v, int i) {
        const float4 sc = *reinterpret_cast<const float4*>(scp + (size_t)i * 4);
        const float4 sh = *reinterpret_cast<const float4*>(shp + (size_t)i * 4);
        s16x4 o;
        o[0] = f2b((v.x - mean) * rs * (1.f + sc.x) + sh.x);
        o[1] = f2b((v.y - mean) * rs * (1.f + sc.y) + sh.y);
        o[2] = f2b((v.z - mean) * rs * (1.f + sc.z) + sh.z);
        o[3] = f2b((v.w - mean) * rs * (1.f + sc.w) + sh.w);
        *reinterpret_cast<s16x4*>(orow + (size_t)i * 4) = o;
    };
    emit(v0, tid);
    emit(v1, tid + 256);
    if (tid < 48) emit(v2, tid + 512);
}

// -------- f32 (K x ldn) slice [colOff, colOff+N) -> bf16 (N x K), N-guarded --------
__global__ __launch_bounds__(256)
void transpose_cast_kernel(const float* __restrict__ in, unsigned short* __restrict__ out,
                           int K, int N, int ldn, int colOff)
{
    __shared__ float sT[32][33];
    const int n0 = blockIdx.x * 32;
    const int k0 = blockIdx.y * 32;
    const int tx = threadIdx.x & 31;
    const int ty = threadIdx.x >> 5;
    #pragma unroll
    for (int i = 0; i < 4; i++) {
        int kr = ty + i * 8;
        sT[kr][tx] = (n0 + tx < N) ? in[(size_t)(k0 + kr) * ldn + colOff + n0 + tx] : 0.f;
    }
    __syncthreads();
    #pragma unroll
    for (int i = 0; i < 4; i++) {
        int nr = ty + i * 8;
        if (n0 + nr < N)
            out[(size_t)(n0 + nr) * K + k0 + tx] = (unsigned short)f2b(sT[tx][nr]);
    }
}

// ---------------- GEMM: C = A(MxK) @ Bt(NxK)^T, fused epilogues ----------------
// A from bf16 (A) or f32 (A32). Output col = colOff + local col, row stride ldc.
// order: relu -> geglu(silu(a)*v) -> gate -> residual -> store f32/bf16.
#define GBM 128
#define GBN 128
#define GBK 64
#define LDK 72    // +8 halfword pad: 144B row stride -> 2-way bank aliasing (free, m136)

__global__ __launch_bounds__(256)
void gemm_kernel(const unsigned short* __restrict__ A, const float* __restrict__ A32,
                 const unsigned short* __restrict__ Bt,
                 int M, int N, int K, int ldc, int colOff,
                 float* __restrict__ outF, unsigned short* __restrict__ outB,
                 const float* __restrict__ resid, const float* __restrict__ gmod,
                 const unsigned short* __restrict__ gegluA,
                 int gateIdx, int rowsPerBatch, int reluCols)
{
    __shared__ unsigned short sA[GBM * LDK];
    __shared__ unsigned short sB[GBN * LDK];
    const int tid = threadIdx.x;
    const int m0 = blockIdx.x * GBM;   // x = M-tile (fast) -> B-panel L2 reuse
    const int n0 = blockIdx.y * GBN;
    const int lane = tid & 63;
    const int w = tid >> 6;
    const int wr = (w >> 1) * 64;
    const int wc = (w & 1) * 64;
    const int lr = lane & 15;
    const int lk = (lane >> 4) * 8;

    f32x4 acc[4][4];
    #pragma unroll
    for (int i = 0; i < 4; i++)
        #pragma unroll
        for (int j = 0; j < 4; j++)
            acc[i][j] = (f32x4){0.f, 0.f, 0.f, 0.f};

    for (int k0 = 0; k0 < K; k0 += GBK) {
        #pragma unroll
        for (int c = 0; c < 4; c++) {
            const int e = tid * 8 + c * 2048;
            const int r = e >> 6;
            const int kk = e & 63;
            const int gk = k0 + kk;
            {   // ---- A tile ----
                const int gr = m0 + r;
                s16x8 va;
                if (A32) {
                    if (gr < M && gk + 8 <= K) {
                        const float4 f0 = *reinterpret_cast<const float4*>(A32 + (size_t)gr * K + gk);
                        const float4 f1 = *reinterpret_cast<const float4*>(A32 + (size_t)gr * K + gk + 4);
                        va[0]=f2b(f0.x); va[1]=f2b(f0.y); va[2]=f2b(f0.z); va[3]=f2b(f0.w);
                        va[4]=f2b(f1.x); va[5]=f2b(f1.y); va[6]=f2b(f1.z); va[7]=f2b(f1.w);
                    } else {
                        #pragma unroll
                        for (int j = 0; j < 8; j++) {
                            float xv = 0.f;
                            if (gr < M && gk + j < K) xv = A32[(size_t)gr * K + gk + j];
                            va[j] = f2b(xv);
                        }
                    }
                } else {
                    if (gr < M && gk + 8 <= K) {
                        va = *reinterpret_cast<const s16x8*>(A + (size_t)gr * K + gk);
                    } else {
                        #pragma unroll
                        for (int j = 0; j < 8; j++) {
                            short xv = 0;
                            if (gr < M && gk + j < K) xv = (short)A[(size_t)gr * K + gk + j];
                            va[j] = xv;
                        }
                    }
                }
                *reinterpret_cast<s16x8*>(&sA[r * LDK + kk]) = va;
            }
            {   // ---- B tile ----
                const int gn = n0 + r;
                s16x8 vb;
                if (gn < N && gk + 8 <= K) {
                    vb = *reinterpret_cast<const s16x8*>(Bt + (size_t)gn * K + gk);
                } else {
                    #pragma unroll
                    for (int j = 0; j < 8; j++) {
                        short xv = 0;
                        if (gn < N && gk + j < K) xv = (short)Bt[(size_t)gn * K + gk + j];
                        vb[j] = xv;
                    }
                }
                *reinterpret_cast<s16x8*>(&sB[r * LDK + kk]) = vb;
            }
        }
        __syncthreads();
        #pragma unroll
        for (int ks = 0; ks < GBK; ks += 32) {
            s16x8 af[4], bfv[4];
            #pragma unroll
            for (int mi = 0; mi < 4; mi++)
                af[mi] = *reinterpret_cast<const s16x8*>(&sA[(wr + mi * 16 + lr) * LDK + ks + lk]);
            #pragma unroll
            for (int ni = 0; ni < 4; ni++)
                bfv[ni] = *reinterpret_cast<const s16x8*>(&sB[(wc + ni * 16 + lr) * LDK + ks + lk]);
            #pragma unroll
            for (int mi = 0; mi < 4; mi++)
                #pragma unroll
                for (int ni = 0; ni < 4; ni++)
                    acc[mi][ni] = __builtin_amdgcn_mfma_f32_16x16x32_bf16(
                        af[mi], bfv[ni], acc[mi][ni], 0, 0, 0);
        }
        __syncthreads();
    }

    // epilogue: C/D layout col = lane&15, row = (lane>>4)*4 + reg  [m89/m91]
    const int row0 = m0 + wr + (lane >> 4) * 4;
    const int col0 = wc + lr;
    #pragma unroll
    for (int mi = 0; mi < 4; mi++) {
        #pragma unroll
        for (int ni = 0; ni < 4; ni++) {
            const int gcol = n0 + col0 + ni * 16;
            if (gcol >= N) continue;
            const int ocol = colOff + gcol;
            #pragma unroll
            for (int r = 0; r < 4; r++) {
                const int row = row0 + mi * 16 + r;
                if (row >= M) continue;
                float v = acc[mi][ni][r];
                if (gcol < reluCols) v = fmaxf(v, 0.f);
                if (gegluA) {
                    float a = b2f((short)gegluA[(size_t)row * ldc + ocol]);
                    v *= a / (1.f + __expf(-a));
                }
                if (gmod) v *= gmod[(row / rowsPerBatch) * MOD6 + gateIdx * D_MODEL + ocol];
                if (resid) v += resid[(size_t)row * ldc + ocol];
                if (outF) outF[(size_t)row * ldc + ocol] = v;
                if (outB) outB[(size_t)row * ldc + ocol] = (unsigned short)f2b(v);
            }
        }
    }
}

// ---------------- ReLU linear attention (Sana) ----------------
__global__ __launch_bounds__(256)
void linattn_kernel(const unsigned short* __restrict__ qkv, unsigned short* __restrict__ o)
{
    __shared__ unsigned short sK[128 * 32];
    __shared__ unsigned short sV[128 * 32];
    __shared__ float sKV[32 * 32];
    __shared__ float sKsum[32];
    const int b = blockIdx.x / NHEAD;
    const int h = blockIdx.x % NHEAD;
    const int tid = threadIdx.x;
    const int d = tid & 31;
    const int eg = tid >> 5;
    const size_t rowBase = (size_t)b * NIMG;
    const size_t stride = 3 * D_MODEL;   // 6720
    const size_t qOff = (size_t)h * HD;
    const size_t kOff = qOff + D_MODEL;
    const size_t vOff = qOff + 2 * D_MODEL;

    float a0 = 0.f, a1 = 0.f, a2 = 0.f, a3 = 0.f, ks = 0.f;
    for (int nc = 0; nc < NIMG; nc += 128) {
        #pragma unroll
        for (int c = 0; c < 2; c++) {
            int e = tid * 8 + c * 2048;
            int r = e >> 5, cc = e & 31;
            size_t g = (rowBase + nc + r) * stride;
            *reinterpret_cast<s16x8*>(&sK[r * 32 + cc]) =
                *reinterpret_cast<const s16x8*>(qkv + g + kOff + cc);
            *reinterpret_cast<s16x8*>(&sV[r * 32 + cc]) =
                *reinterpret_cast<const s16x8*>(qkv + g + vOff + cc);
        }
        __syncthreads();
        for (int n = 0; n < 128; n++) {
            float kd = b2f((short)sK[n * 32 + d]);
            s16x4 v4 = *reinterpret_cast<const s16x4*>(&sV[n * 32 + eg * 4]);
            a0 += kd * b2f(v4[0]);
            a1 += kd * b2f(v4[1]);
            a2 += kd * b2f(v4[2]);
            a3 += kd * b2f(v4[3]);
            ks += kd;
        }
        __syncthreads();
    }
    sKV[d * 32 + eg * 4 + 0] = a0;
    sKV[d * 32 + eg * 4 + 1] = a1;
    sKV[d * 32 + eg * 4 + 2] = a2;
    sKV[d * 32 + eg * 4 + 3] = a3;
    if (tid < 32) sKsum[tid] = ks;
    __syncthreads();

    #pragma unroll 1
    for (int rr = 0; rr < 4; rr++) {
        const int n = tid + rr * 256;
        const unsigned short* qp = qkv + (rowBase + n) * stride + qOff;
        float q[32];
        #pragma unroll
        for (int j4 = 0; j4 < 4; j4++) {
            s16x8 q8 = *reinterpret_cast<const s16x8*>(qp + j4 * 8);
            #pragma unroll
            for (int j = 0; j < 8; j++) q[j4 * 8 + j] = b2f(q8[j]);
        }
        float z = 1e-6f;
        #pragma unroll
        for (int dd = 0; dd < 32; dd++) z += q[dd] * sKsum[dd];
        float ov[32];
        #pragma unroll
        for (int e = 0; e < 32; e++) ov[e] = 0.f;
        #pragma unroll 4
        for (int dd = 0; dd < 32; dd++) {
            const float qd = q[dd];
            #pragma unroll
            for (int e4 = 0; e4 < 8; e4++) {
                const float4 kv4 = *reinterpret_cast<const float4*>(&sKV[dd * 32 + e4 * 4]);
                ov[e4 * 4 + 0] += qd * kv4.x;
                ov[e4 * 4 + 1] += qd * kv4.y;
                ov[e4 * 4 + 2] += qd * kv4.z;
                ov[e4 * 4 + 3] += qd * kv4.w;
            }
        }
        const float rz = 1.0f / z;
        unsigned short* op = o + (rowBase + n) * D_MODEL + qOff;
        #pragma unroll
        for (int e8 = 0; e8 < 4; e8++) {
            s16x8 o8;
            #pragma unroll
            for (int j = 0; j < 8; j++) o8[j] = f2b(ov[e8 * 8 + j] * rz);
            *reinterpret_cast<s16x8*>(op + e8 * 8) = o8;
        }
    }
}

// ---------------- cross attention to text tokens (additive mask) ----------------
__global__ __launch_bounds__(256)
void crossattn_kernel(const unsigned short* __restrict__ q2, const unsigned short* __restrict__ kvc,
                      const float* __restrict__ mask, unsigned short* __restrict__ oc)
{
    __shared__ float sKf[NTXT * HD];
    __shared__ unsigned short sVb[NTXT * HD];
    __shared__ float sM[NTXT];
    const int bh = blockIdx.y;
    const int b = bh / NHEAD;
    const int h = bh % NHEAD;
    const int tid = threadIdx.x;
    for (int i = tid; i < (NTXT * HD) / 8; i += 256) {
        int t = i >> 2;
        int c = (i & 3) * 8;
        size_t g = ((size_t)b * NTXT + t) * (2 * D_MODEL) + (size_t)h * HD + c;
        s16x8 k8 = *reinterpret_cast<const s16x8*>(kvc + g);
        #pragma unroll
        for (int j = 0; j < 8; j++) sKf[t * HD + c + j] = b2f(k8[j]);
        s16x8 v8 = *reinterpret_cast<const s16x8*>(kvc + g + D_MODEL);
        *reinterpret_cast<s16x8*>(&sVb[t * HD + c]) = v8;
    }
    for (int i = tid; i < NTXT; i += 256) sM[i] = mask[b * NTXT + i];
    __syncthreads();

    const int n = blockIdx.x * 256 + tid;
    const unsigned short* qp = q2 + ((size_t)b * NIMG + n) * D_MODEL + (size_t)h * HD;
    float q[32];
    #pragma unroll
    for (int j4 = 0; j4 < 4; j4++) {
        s16x8 q8 = *reinterpret_cast<const s16x8*>(qp + j4 * 8);
        #pragma unroll
        for (int j = 0; j < 8; j++) q[j4 * 8 + j] = b2f(q8[j]);
    }
    const float scale = 0.1767766952966369f;   // 1/sqrt(32)
    float m = -1e30f, l = 0.f;
    for (int t = 0; t < NTXT; t++) {
        const float* kr = &sKf[t * HD];
        float s = 0.f;
        #pragma unroll
        for (int d4 = 0; d4 < 8; d4++) {
            const float4 k4 = *reinterpret_cast<const float4*>(kr + d4 * 4);
            s += q[d4*4+0]*k4.x + q[d4*4+1]*k4.y + q[d4*4+2]*k4.z + q[d4*4+3]*k4.w;
        }
        s = s * scale + sM[t];
        const float mn = fmaxf(m, s);
        l = l * __expf(m - mn) + __expf(s - mn);
        m = mn;
    }
    float ov[32];
    #pragma unroll
    for (int e = 0; e < 32; e++) ov[e] = 0.f;
    for (int t = 0; t < NTXT; t++) {
        const float* kr = &sKf[t * HD];
        float s = 0.f;
        #pragma unroll
        for (int d4 = 0; d4 < 8; d4++) {
            const float4 k4 = *reinterpret_cast<const float4*>(kr + d4 * 4);
            s += q[d4*4+0]*k4.x + q[d4*4+1]*k4.y + q[d4*4+2]*k4.z + q[d4*4+3]*k4.w;
        }
        s = s * scale + sM[t];
        const float p = __expf(s - m);
        const unsigned short* vr = &sVb[t * HD];
        #pragma unroll
        for (int e8 = 0; e8 < 4; e8++) {
            s16x8 v8 = *reinterpret_cast<const s16x8*>(vr + e8 * 8);
            #pragma unroll
            for (int j = 0; j < 8; j++) ov[e8 * 8 + j] += p * b2f(v8[j]);
        }
    }
    const float rl = 1.0f / l;
    unsigned short* op = oc + ((size_t)b * NIMG + n) * D_MODEL + (size_t)h * HD;
    #pragma unroll
    for (int e8 = 0; e8 < 4; e8++) {
        s16x8 o8;
        #pragma unroll
        for (int j = 0; j < 8; j++) o8[j] = f2b(ov[e8 * 8 + j] * rl);
        *reinterpret_cast<s16x8*>(op + e8 * 8) = o8;
    }
}

static inline int cdiv(int a, int b) { return (a + b - 1) / b; }

extern "C" void kernel_launch(void* const* d_in, const int* in_sizes, int n_in,
                              void* d_out, int out_size, void* d_ws, size_t ws_size,
                              hipStream_t stream)
{
    (void)in_sizes; (void)n_in; (void)out_size; (void)ws_size;
    const float* x0    = (const float*)d_in[0];
    const float* enc   = (const float*)d_in[1];
    const float* msk   = (const float*)d_in[2];
    const int*   tst   = (const int*)d_in[3];
    const float* W_t   = (const float*)d_in[4];
    const float* b_t   = (const float*)d_in[5];
    const float* sst   = (const float*)d_in[6];
    const float* W_qkv = (const float*)d_in[7];
    const float* W_o   = (const float*)d_in[8];
    const float* W_q   = (const float*)d_in[9];
    const float* W_kv  = (const float*)d_in[10];
    const float* W_co  = (const float*)d_in[11];
    const float* W_ff1 = (const float*)d_in[12];
    const float* W_ff2 = (const float*)d_in[13];
    float* out = (float*)d_out;
    char* ws = (char*)d_ws;

    // workspace layout (bytes); peak use 56,471,552 B (~53.9 MiB)
    const size_t O_MOD = 0;                    //    107,520 (2 x 13440 f32)
    const size_t O_WT  = 131072;               // 15,052,800 (max B^T slice: 3360x2240 bf16)
    const size_t O_A1  = O_WT + 15052800;      //  9,175,040 (2048x2240 bf16)
    const size_t O_A2  = O_A1 + 9175040;       //  9,175,040
    const size_t O_UA  = O_A2 + 9175040;       // 27,525,120 (qkv 2048x6720 | q2 | act 2048x5600)
    const size_t O_KVC = O_UA + 16777216;      //  5,376,000 (overlay; act overwrites only after kvc dead)

    float* mod = (float*)(ws + O_MOD);
    unsigned short* wT    = (unsigned short*)(ws + O_WT);
    unsigned short* bufA1 = (unsigned short*)(ws + O_A1);
    unsigned short* bufA2 = (unsigned short*)(ws + O_A2);
    unsigned short* bufUA = (unsigned short*)(ws + O_UA);
    unsigned short* kvcB  = (unsigned short*)(ws + O_KVC);

    // 1. modulation table
    tmod_kernel<<<dim3(cdiv(MOD6, 256), 2), 256, 0, stream>>>(tst, W_t, b_t, sst, mod);
    // 2. hmod = LN(x0)*(1+sc1)+sh1 -> bufA1
    ln_mod_kernel<<<2048, 256, 0, stream>>>(x0, mod, bufA1, 1, 0);
    // 3. qkv = hmod @ W_qkv (relu on q,k) -> bufUA, two N=3360 slices
    transpose_cast_kernel<<<dim3(105, 70), 256, 0, stream>>>(W_qkv, wT, 2240, 3360, 6720, 0);
    gemm_kernel<<<dim3(16, 27), 256, 0, stream>>>(bufA1, nullptr, wT, 2048, 3360, 2240,
        6720, 0, nullptr, bufUA, nullptr, nullptr, nullptr, 0, NIMG, 3360);
    transpose_cast_kernel<<<dim3(105, 70), 256, 0, stream>>>(W_qkv, wT, 2240, 3360, 6720, 3360);
    gemm_kernel<<<dim3(16, 27), 256, 0, stream>>>(bufA1, nullptr, wT, 2048, 3360, 2240,
        6720, 3360, nullptr, bufUA, nullptr, nullptr, nullptr, 0, NIMG, 1120);
    // 4. linear attention -> bufA1
    linattn_kernel<<<140, 256, 0, stream>>>(bufUA, bufA1);
    // 5. x1 = x0 + g1*(o @ W_o) -> out (f32) + bufA2 (bf16)
    transpose_cast_kernel<<<dim3(70, 70), 256, 0, stream>>>(W_o, wT, 2240, 2240, 2240, 0);
    gemm_kernel<<<dim3(16, 18), 256, 0, stream>>>(bufA1, nullptr, wT, 2048, 2240, 2240,
        2240, 0, out, bufA2, x0, mod, nullptr, 2, NIMG, 0);
    // 6. q2 = x1 @ W_q -> bufUA
    transpose_cast_kernel<<<dim3(70, 70), 256, 0, stream>>>(W_q, wT, 2240, 2240, 2240, 0);
    gemm_kernel<<<dim3(16, 18), 256, 0, stream>>>(bufA2, nullptr, wT, 2048, 2240, 2240,
        2240, 0, nullptr, bufUA, nullptr, nullptr, nullptr, 0, NIMG, 0);
    // 7. kvc = enc @ W_kv -> kvcB (ld 4480), two N=2240 slices, A from f32
    transpose_cast_kernel<<<dim3(70, 70), 256, 0, stream>>>(W_kv, wT, 2240, 2240, 4480, 0);
    gemm_kernel<<<dim3(5, 18), 256, 0, stream>>>(nullptr, enc, wT, 600, 2240, 2240,
        4480, 0, nullptr, kvcB, nullptr, nullptr, nullptr, 0, NTXT, 0);
    transpose_cast_kernel<<<dim3(70, 70), 256, 0, stream>>>(W_kv, wT, 2240, 2240, 4480, 2240);
    gemm_kernel<<<dim3(5, 18), 256, 0, stream>>>(nullptr, enc, wT, 600, 2240, 2240,
        4480, 2240, nullptr, kvcB, nullptr, nullptr, nullptr, 0, NTXT, 0);
    // 8. cross attention -> bufA1
    crossattn_kernel<<<dim3(4, 140), 256, 0, stream>>>(bufUA, kvcB, msk, bufA1);
    // 9. x2 = x1 + o_c @ W_co -> out (in-place residual)
    transpose_cast_kernel<<<dim3(70, 70), 256, 0, stream>>>(W_co, wT, 2240, 2240, 2240, 0);
    gemm_kernel<<<dim3(16, 18), 256, 0, stream>>>(bufA1, nullptr, wT, 2048, 2240, 2240,
        2240, 0, out, nullptr, out, nullptr, nullptr, 0, NIMG, 0);
    // 10. f = LN(x2)*(1+sc2)+sh2 -> bufA2
    ln_mod_kernel<<<2048, 256, 0, stream>>>(out, mod, bufA2, 4, 3);
    // 11+12. u = f @ W_ff1 in 4 N=2800 quarters into act (bufUA, ld 5600);
    //        quarters 2,3 (g-half) fuse act = silu(a)*g in the epilogue.
    for (int qi = 0; qi < 4; qi++) {
        const int wcol = qi * 2800;               // weight-space col offset
        const int ocol = (qi & 1) * 2800;         // output col offset within act
        const unsigned short* ga = (qi >= 2) ? bufUA : nullptr;
        transpose_cast_kernel<<<dim3(88, 70), 256, 0, stream>>>(W_ff1, wT, 2240, 2800, 11200, wcol);
        gemm_kernel<<<dim3(16, 22), 256, 0, stream>>>(bufA2, nullptr, wT, 2048, 2800, 2240,
            5600, ocol, nullptr, bufUA, nullptr, nullptr, ga, 0, NIMG, 0);
    }
    // 13. x = x2 + g2*(act @ W_ff2) -> out, two N=1120 slices, K=5600
    for (int si = 0; si < 2; si++) {
        const int ocol = si * 1120;
        transpose_cast_kernel<<<dim3(35, 175), 256, 0, stream>>>(W_ff2, wT, 5600, 1120, 2240, ocol);
        gemm_kernel<<<dim3(16, 9), 256, 0, stream>>>(bufUA, nullptr, wT, 2048, 1120, 5600,
            2240, ocol, out, nullptr, out, mod, nullptr, 5, NIMG, 0);
    }
}

// Round 10
// 1892.499 us; speedup vs baseline: 1.4884x; 1.4884x over previous
//
#include <hip/hip_runtime.h>
#include <cstdint>
#include <cstddef>

typedef __attribute__((ext_vector_type(8))) short  s16x8;
typedef __attribute__((ext_vector_type(4))) short  s16x4;
typedef __attribute__((ext_vector_type(4))) float  f32x4;

#define D_MODEL 2240
#define MOD6    13440
#define NHEAD   70
#define HD      32
#define NIMG    1024
#define NTXT    300
#define DFF_    5600

__device__ __forceinline__ float b2f(short s) {
    union { unsigned int u; float f; } c;
    c.u = ((unsigned int)(unsigned short)s) << 16;
    return c.f;
}
__device__ __forceinline__ short f2b(float f) {
    union { float f; unsigned int u; } c; c.f = f;
    unsigned int r = c.u + 0x7fffu + ((c.u >> 16) & 1u);
    return (short)(r >> 16);
}
// async global->LDS, 16B per lane; lds dest must be wave-uniform base (HW adds lane*16)
__device__ __forceinline__ void gl16(const unsigned short* g, unsigned short* l) {
    __builtin_amdgcn_global_load_lds(
        (const __attribute__((address_space(1))) void*)g,
        (__attribute__((address_space(3))) void*)l,
        16, 0, 0);
}

// ---------------- timestep embedding + modulation table ----------------
__global__ __launch_bounds__(256)
void tmod_kernel(const int* __restrict__ tstep, const float* __restrict__ Wt,
                 const float* __restrict__ bt, const float* __restrict__ sst,
                 float* __restrict__ mod)
{
    __shared__ float sT[256];
    const int b = blockIdx.y;
    const int tid = threadIdx.x;
    const float tv = (float)tstep[b];
    {
        const float NL = -logf(10000.0f);
        int c = tid & 127;
        float f = expf(NL * ((float)c * (1.0f / 128.0f)));
        float a = tv * f;
        sT[tid] = (tid < 128) ? cosf(a) : sinf(a);
    }
    __syncthreads();
    int j = blockIdx.x * 256 + tid;
    if (j < MOD6) {
        float s = 0.f;
        #pragma unroll 8
        for (int c = 0; c < 256; c++) s += sT[c] * Wt[c * MOD6 + j];
        mod[b * MOD6 + j] = s + bt[j] + sst[j];
    }
}

// ---------------- LayerNorm (no affine) * (1+sc) + sh  -> bf16 ----------------
__global__ __launch_bounds__(256)
void ln_mod_kernel(const float* __restrict__ x, const float* __restrict__ mod,
                   unsigned short* __restrict__ out, int scIdx, int shIdx)
{
    const int row = blockIdx.x;          // 0..2047
    const int b = row >> 10;
    const int tid = threadIdx.x;
    const float* xr = x + (size_t)row * D_MODEL;
    const float4 v0 = *reinterpret_cast<const float4*>(xr + (size_t)tid * 4);
    const float4 v1 = *reinterpret_cast<const float4*>(xr + (size_t)(tid + 256) * 4);
    float4 v2 = make_float4(0.f, 0.f, 0.f, 0.f);
    if (tid < 48) v2 = *reinterpret_cast<const float4*>(xr + (size_t)(tid + 512) * 4);
    float s  = v0.x + v0.y + v0.z + v0.w + v1.x + v1.y + v1.z + v1.w
             + v2.x + v2.y + v2.z + v2.w;
    float sq = v0.x*v0.x + v0.y*v0.y + v0.z*v0.z + v0.w*v0.w
             + v1.x*v1.x + v1.y*v1.y + v1.z*v1.z + v1.w*v1.w
             + v2.x*v2.x + v2.y*v2.y + v2.z*v2.z + v2.w*v2.w;
    #pragma unroll
    for (int off = 32; off > 0; off >>= 1) {
        s  += __shfl_down(s, off);
        sq += __shfl_down(sq, off);
    }
    __shared__ float red[8];
    if ((tid & 63) == 0) { red[tid >> 6] = s; red[(tid >> 6) + 4] = sq; }
    __syncthreads();
    s  = red[0] + red[1] + red[2] + red[3];
    sq = red[4] + red[5] + red[6] + red[7];
    const float inv = 1.0f / (float)D_MODEL;
    const float mean = s * inv;
    const float var = sq * inv - mean * mean;
    const float rs = rsqrtf(var + 1e-6f);
    const float* scp = mod + b * MOD6 + scIdx * D_MODEL;
    const float* shp = mod + b * MOD6 + shIdx * D_MODEL;
    unsigned short* orow = out + (size_t)row * D_MODEL;
    auto emit = [&](const float4& v, int i) {
        const float4 sc = *reinterpret_cast<const float4*>(scp + (size_t)i * 4);
        const float4 sh = *reinterpret_cast<const float4*>(shp + (size_t)i * 4);
        s16x4 o;
        o[0] = f2b((v.x - mean) * rs * (1.f + sc.x) + sh.x);
        o[1] = f2b((v.y - mean) * rs * (1.f + sc.y) + sh.y);
        o[2] = f2b((v.z - mean) * rs * (1.f + sc.z) + sh.z);
        o[3] = f2b((v.w - mean) * rs * (1.f + sc.w) + sh.w);
        *reinterpret_cast<s16x4*>(orow + (size_t)i * 4) = o;
    };
    emit(v0, tid);
    emit(v1, tid + 256);
    if (tid < 48) emit(v2, tid + 512);
}

// -------- W (Krows x ldn) slice -> bf16 (Npad x Kpad), zero-padded --------
// out[n*Kpad + k] = (rowOff+k < Krows && n < N) ? W[(rowOff+k)*ldn + colOff + n] : 0
__global__ __launch_bounds__(256)
void transpose_cast_kernel(const float* __restrict__ in, unsigned short* __restrict__ out,
                           int Krows, int rowOff, int Kpad, int N, int Npad,
                           int ldn, int colOff)
{
    __shared__ float sT[32][33];
    const int n0 = blockIdx.x * 32;
    const int k0 = blockIdx.y * 32;
    const int tx = threadIdx.x & 31;
    const int ty = threadIdx.x >> 5;
    #pragma unroll
    for (int i = 0; i < 4; i++) {
        int kr = rowOff + k0 + ty + i * 8;
        int nc = n0 + tx;
        sT[ty + i * 8][tx] = (kr < Krows && nc < N) ? in[(size_t)kr * ldn + colOff + nc] : 0.f;
    }
    __syncthreads();
    #pragma unroll
    for (int i = 0; i < 4; i++) {
        int nr = n0 + ty + i * 8;
        int kc = k0 + tx;
        if (nr < Npad && kc < Kpad)
            out[(size_t)nr * Kpad + kc] = (unsigned short)f2b(sT[tx][ty + i * 8]);
    }
}

// ============ main GEMM (m97 structure): C = A(MxK, ld=lda) @ Bt(Npad x K)^T ============
// Requires: M%128==0, Npad%128==0, K%64==0 (Bt zero-padded). Linear LDS + global_load_lds x16.
// epilogue order: relu -> geglu -> preAdd -> gate -> residual -> store f32/bf16 (col<N guard).
__global__ __launch_bounds__(256)
void gemm_lds_kernel(const unsigned short* __restrict__ A, const unsigned short* __restrict__ Bt,
                     int M, int Npad, int K, int lda,
                     int N, int ldc, int colOff,
                     float* __restrict__ outF, unsigned short* __restrict__ outB,
                     const float* __restrict__ resid, const float* __restrict__ preAdd,
                     const float* __restrict__ gmod,
                     const unsigned short* __restrict__ gegluA,
                     int gateIdx, int rowsPerBatch, int reluCols)
{
    __shared__ unsigned short sA[128 * 64];
    __shared__ unsigned short sB[128 * 64];
    const int tid = threadIdx.x;
    const int m0 = blockIdx.x * 128;   // x = M-tile (fast) -> B-panel L2 reuse
    const int n0 = blockIdx.y * 128;
    const int lane = tid & 63;
    const int w = tid >> 6;
    const int wr = (w >> 1) * 64;
    const int wc = (w & 1) * 64;
    const int lr = lane & 15;
    const int lk = (lane >> 4) * 8;
    // staging: wave w owns rows [w*32, w*32+32); issue i covers 8 rows (64 lanes x 16B = 1KB)
    const int srow = w * 32;
    const int lrow = lane >> 3;          // 0..7
    const int lcol = (lane & 7) * 8;     // 0,8,..,56

    f32x4 acc[4][4];
    #pragma unroll
    for (int i = 0; i < 4; i++)
        #pragma unroll
        for (int j = 0; j < 4; j++)
            acc[i][j] = (f32x4){0.f, 0.f, 0.f, 0.f};

    const unsigned short* pa = A  + (size_t)(m0 + srow + lrow) * lda + lcol;
    const unsigned short* pb = Bt + (size_t)(n0 + srow + lrow) * K   + lcol;

    for (int k0 = 0; k0 < K; k0 += 64) {
        #pragma unroll
        for (int i = 0; i < 4; i++) {
            gl16(pa + (size_t)(i * 8) * lda + k0, &sA[(srow + i * 8) * 64]);
            gl16(pb + (size_t)(i * 8) * K   + k0, &sB[(srow + i * 8) * 64]);
        }
        __syncthreads();   // drains vmcnt(0) before barrier
        #pragma unroll
        for (int ks = 0; ks < 64; ks += 32) {
            s16x8 af[4], bfv[4];
            #pragma unroll
            for (int mi = 0; mi < 4; mi++)
                af[mi] = *reinterpret_cast<const s16x8*>(&sA[(wr + mi * 16 + lr) * 64 + ks + lk]);
            #pragma unroll
            for (int ni = 0; ni < 4; ni++)
                bfv[ni] = *reinterpret_cast<const s16x8*>(&sB[(wc + ni * 16 + lr) * 64 + ks + lk]);
            #pragma unroll
            for (int mi = 0; mi < 4; mi++)
                #pragma unroll
                for (int ni = 0; ni < 4; ni++)
                    acc[mi][ni] = __builtin_amdgcn_mfma_f32_16x16x32_bf16(
                        af[mi], bfv[ni], acc[mi][ni], 0, 0, 0);
        }
        __syncthreads();
    }

    // epilogue: C/D layout col = lane&15, row = (lane>>4)*4 + reg  [m89/m91]
    const int row0 = m0 + wr + (lane >> 4) * 4;
    const int col0 = wc + lr;
    #pragma unroll
    for (int mi = 0; mi < 4; mi++) {
        #pragma unroll
        for (int ni = 0; ni < 4; ni++) {
            const int gcol = n0 + col0 + ni * 16;
            if (gcol >= N) continue;
            const int ocol = colOff + gcol;
            #pragma unroll
            for (int r = 0; r < 4; r++) {
                const int row = row0 + mi * 16 + r;
                if (row >= M) continue;
                float v = acc[mi][ni][r];
                if (gcol < reluCols) v = fmaxf(v, 0.f);
                if (gegluA) {
                    float a = b2f((short)gegluA[(size_t)row * ldc + ocol]);
                    v *= a / (1.f + __expf(-a));
                }
                if (preAdd) v += preAdd[(size_t)row * ldc + ocol];
                if (gmod) v *= gmod[(row / rowsPerBatch) * MOD6 + gateIdx * D_MODEL + ocol];
                if (resid) v += resid[(size_t)row * ldc + ocol];
                if (outF) outF[(size_t)row * ldc + ocol] = v;
                if (outB) outB[(size_t)row * ldc + ocol] = (unsigned short)f2b(v);
            }
        }
    }
}

// ============ small guarded GEMM (register staging) — used for enc @ W_kv only ============
#define GBM 128
#define GBN 128
#define GBK 64
#define LDK 72

__global__ __launch_bounds__(256)
void gemm_kernel(const unsigned short* __restrict__ A, const float* __restrict__ A32,
                 const unsigned short* __restrict__ Bt,
                 int M, int N, int K, int ldc, int colOff,
                 float* __restrict__ outF, unsigned short* __restrict__ outB,
                 const float* __restrict__ resid, const float* __restrict__ gmod,
                 const unsigned short* __restrict__ gegluA,
                 int gateIdx, int rowsPerBatch, int reluCols)
{
    __shared__ unsigned short sA[GBM * LDK];
    __shared__ unsigned short sB[GBN * LDK];
    const int tid = threadIdx.x;
    const int m0 = blockIdx.x * GBM;
    const int n0 = blockIdx.y * GBN;
    const int lane = tid & 63;
    const int w = tid >> 6;
    const int wr = (w >> 1) * 64;
    const int wc = (w & 1) * 64;
    const int lr = lane & 15;
    const int lk = (lane >> 4) * 8;

    f32x4 acc[4][4];
    #pragma unroll
    for (int i = 0; i < 4; i++)
        #pragma unroll
        for (int j = 0; j < 4; j++)
            acc[i][j] = (f32x4){0.f, 0.f, 0.f, 0.f};

    for (int k0 = 0; k0 < K; k0 += GBK) {
        #pragma unroll
        for (int c = 0; c < 4; c++) {
            const int e = tid * 8 + c * 2048;
            const int r = e >> 6;
            const int kk = e & 63;
            const int gk = k0 + kk;
            {
                const int gr = m0 + r;
                s16x8 va;
                if (A32) {
                    if (gr < M && gk + 8 <= K) {
                        const float4 f0 = *reinterpret_cast<const float4*>(A32 + (size_t)gr * K + gk);
                        const float4 f1 = *reinterpret_cast<const float4*>(A32 + (size_t)gr * K + gk + 4);
                        va[0]=f2b(f0.x); va[1]=f2b(f0.y); va[2]=f2b(f0.z); va[3]=f2b(f0.w);
                        va[4]=f2b(f1.x); va[5]=f2b(f1.y); va[6]=f2b(f1.z); va[7]=f2b(f1.w);
                    } else {
                        #pragma unroll
                        for (int j = 0; j < 8; j++) {
                            float xv = 0.f;
                            if (gr < M && gk + j < K) xv = A32[(size_t)gr * K + gk + j];
                            va[j] = f2b(xv);
                        }
                    }
                } else {
                    if (gr < M && gk + 8 <= K) {
                        va = *reinterpret_cast<const s16x8*>(A + (size_t)gr * K + gk);
                    } else {
                        #pragma unroll
                        for (int j = 0; j < 8; j++) {
                            short xv = 0;
                            if (gr < M && gk + j < K) xv = (short)A[(size_t)gr * K + gk + j];
                            va[j] = xv;
                        }
                    }
                }
                *reinterpret_cast<s16x8*>(&sA[r * LDK + kk]) = va;
            }
            {
                const int gn = n0 + r;
                s16x8 vb;
                if (gn < N && gk + 8 <= K) {
                    vb = *reinterpret_cast<const s16x8*>(Bt + (size_t)gn * K + gk);
                } else {
                    #pragma unroll
                    for (int j = 0; j < 8; j++) {
                        short xv = 0;
                        if (gn < N && gk + j < K) xv = (short)Bt[(size_t)gn * K + gk + j];
                        vb[j] = xv;
                    }
                }
                *reinterpret_cast<s16x8*>(&sB[r * LDK + kk]) = vb;
            }
        }
        __syncthreads();
        #pragma unroll
        for (int ks = 0; ks < GBK; ks += 32) {
            s16x8 af[4], bfv[4];
            #pragma unroll
            for (int mi = 0; mi < 4; mi++)
                af[mi] = *reinterpret_cast<const s16x8*>(&sA[(wr + mi * 16 + lr) * LDK + ks + lk]);
            #pragma unroll
            for (int ni = 0; ni < 4; ni++)
                bfv[ni] = *reinterpret_cast<const s16x8*>(&sB[(wc + ni * 16 + lr) * LDK + ks + lk]);
            #pragma unroll
            for (int mi = 0; mi < 4; mi++)
                #pragma unroll
                for (int ni = 0; ni < 4; ni++)
                    acc[mi][ni] = __builtin_amdgcn_mfma_f32_16x16x32_bf16(
                        af[mi], bfv[ni], acc[mi][ni], 0, 0, 0);
        }
        __syncthreads();
    }

    const int row0 = m0 + wr + (lane >> 4) * 4;
    const int col0 = wc + lr;
    #pragma unroll
    for (int mi = 0; mi < 4; mi++) {
        #pragma unroll
        for (int ni = 0; ni < 4; ni++) {
            const int gcol = n0 + col0 + ni * 16;
            if (gcol >= N) continue;
            const int ocol = colOff + gcol;
            #pragma unroll
            for (int r = 0; r < 4; r++) {
                const int row = row0 + mi * 16 + r;
                if (row >= M) continue;
                float v = acc[mi][ni][r];
                if (gcol < reluCols) v = fmaxf(v, 0.f);
                if (gegluA) {
                    float a = b2f((short)gegluA[(size_t)row * ldc + ocol]);
                    v *= a / (1.f + __expf(-a));
                }
                if (gmod) v *= gmod[(row / rowsPerBatch) * MOD6 + gateIdx * D_MODEL + ocol];
                if (resid) v += resid[(size_t)row * ldc + ocol];
                if (outF) outF[(size_t)row * ldc + ocol] = v;
                if (outB) outB[(size_t)row * ldc + ocol] = (unsigned short)f2b(v);
            }
        }
    }
}

// ---------------- ReLU linear attention (Sana) ----------------
__global__ __launch_bounds__(256)
void linattn_kernel(const unsigned short* __restrict__ qkv, unsigned short* __restrict__ o)
{
    __shared__ unsigned short sK[128 * 32];
    __shared__ unsigned short sV[128 * 32];
    __shared__ float sKV[32 * 32];
    __shared__ float sKsum[32];
    const int b = blockIdx.x / NHEAD;
    const int h = blockIdx.x % NHEAD;
    const int tid = threadIdx.x;
    const int d = tid & 31;
    const int eg = tid >> 5;
    const size_t rowBase = (size_t)b * NIMG;
    const size_t stride = 3 * D_MODEL;   // 6720
    const size_t qOff = (size_t)h * HD;
    const size_t kOff = qOff + D_MODEL;
    const size_t vOff = qOff + 2 * D_MODEL;

    float a0 = 0.f, a1 = 0.f, a2 = 0.f, a3 = 0.f, ks = 0.f;
    for (int nc = 0; nc < NIMG; nc += 128) {
        #pragma unroll
        for (int c = 0; c < 2; c++) {
            int e = tid * 8 + c * 2048;
            int r = e >> 5, cc = e & 31;
            size_t g = (rowBase + nc + r) * stride;
            *reinterpret_cast<s16x8*>(&sK[r * 32 + cc]) =
                *reinterpret_cast<const s16x8*>(qkv + g + kOff + cc);
            *reinterpret_cast<s16x8*>(&sV[r * 32 + cc]) =
                *reinterpret_cast<const s16x8*>(qkv + g + vOff + cc);
        }
        __syncthreads();
        for (int n = 0; n < 128; n++) {
            float kd = b2f((short)sK[n * 32 + d]);
            s16x4 v4 = *reinterpret_cast<const s16x4*>(&sV[n * 32 + eg * 4]);
            a0 += kd * b2f(v4[0]);
            a1 += kd * b2f(v4[1]);
            a2 += kd * b2f(v4[2]);
            a3 += kd * b2f(v4[3]);
            ks += kd;
        }
        __syncthreads();
    }
    sKV[d * 32 + eg * 4 + 0] = a0;
    sKV[d * 32 + eg * 4 + 1] = a1;
    sKV[d * 32 + eg * 4 + 2] = a2;
    sKV[d * 32 + eg * 4 + 3] = a3;
    if (tid < 32) sKsum[tid] = ks;
    __syncthreads();

    #pragma unroll 1
    for (int rr = 0; rr < 4; rr++) {
        const int n = tid + rr * 256;
        const unsigned short* qp = qkv + (rowBase + n) * stride + qOff;
        float q[32];
        #pragma unroll
        for (int j4 = 0; j4 < 4; j4++) {
            s16x8 q8 = *reinterpret_cast<const s16x8*>(qp + j4 * 8);
            #pragma unroll
            for (int j = 0; j < 8; j++) q[j4 * 8 + j] = b2f(q8[j]);
        }
        float z = 1e-6f;
        #pragma unroll
        for (int dd = 0; dd < 32; dd++) z += q[dd] * sKsum[dd];
        float ov[32];
        #pragma unroll
        for (int e = 0; e < 32; e++) ov[e] = 0.f;
        #pragma unroll 4
        for (int dd = 0; dd < 32; dd++) {
            const float qd = q[dd];
            #pragma unroll
            for (int e4 = 0; e4 < 8; e4++) {
                const float4 kv4 = *reinterpret_cast<const float4*>(&sKV[dd * 32 + e4 * 4]);
                ov[e4 * 4 + 0] += qd * kv4.x;
                ov[e4 * 4 + 1] += qd * kv4.y;
                ov[e4 * 4 + 2] += qd * kv4.z;
                ov[e4 * 4 + 3] += qd * kv4.w;
            }
        }
        const float rz = 1.0f / z;
        unsigned short* op = o + (rowBase + n) * D_MODEL + qOff;
        #pragma unroll
        for (int e8 = 0; e8 < 4; e8++) {
            s16x8 o8;
            #pragma unroll
            for (int j = 0; j < 8; j++) o8[j] = f2b(ov[e8 * 8 + j] * rz);
            *reinterpret_cast<s16x8*>(op + e8 * 8) = o8;
        }
    }
}

// ---------------- cross attention to text tokens (additive mask) ----------------
__global__ __launch_bounds__(256)
void crossattn_kernel(const unsigned short* __restrict__ q2, const unsigned short* __restrict__ kvc,
                      const float* __restrict__ mask, unsigned short* __restrict__ oc)
{
    __shared__ float sKf[NTXT * HD];
    __shared__ unsigned short sVb[NTXT * HD];
    __shared__ float sM[NTXT];
    const int bh = blockIdx.y;
    const int b = bh / NHEAD;
    const int h = bh % NHEAD;
    const int tid = threadIdx.x;
    for (int i = tid; i < (NTXT * HD) / 8; i += 256) {
        int t = i >> 2;
        int c = (i & 3) * 8;
        size_t g = ((size_t)b * NTXT + t) * (2 * D_MODEL) + (size_t)h * HD + c;
        s16x8 k8 = *reinterpret_cast<const s16x8*>(kvc + g);
        #pragma unroll
        for (int j = 0; j < 8; j++) sKf[t * HD + c + j] = b2f(k8[j]);
        s16x8 v8 = *reinterpret_cast<const s16x8*>(kvc + g + D_MODEL);
        *reinterpret_cast<s16x8*>(&sVb[t * HD + c]) = v8;
    }
    for (int i = tid; i < NTXT; i += 256) sM[i] = mask[b * NTXT + i];
    __syncthreads();

    const int n = blockIdx.x * 256 + tid;
    const unsigned short* qp = q2 + ((size_t)b * NIMG + n) * D_MODEL + (size_t)h * HD;
    float q[32];
    #pragma unroll
    for (int j4 = 0; j4 < 4; j4++) {
        s16x8 q8 = *reinterpret_cast<const s16x8*>(qp + j4 * 8);
        #pragma unroll
        for (int j = 0; j < 8; j++) q[j4 * 8 + j] = b2f(q8[j]);
    }
    const float scale = 0.1767766952966369f;   // 1/sqrt(32)
    float m = -1e30f, l = 0.f;
    for (int t = 0; t < NTXT; t++) {
        const float* kr = &sKf[t * HD];
        float s = 0.f;
        #pragma unroll
        for (int d4 = 0; d4 < 8; d4++) {
            const float4 k4 = *reinterpret_cast<const float4*>(kr + d4 * 4);
            s += q[d4*4+0]*k4.x + q[d4*4+1]*k4.y + q[d4*4+2]*k4.z + q[d4*4+3]*k4.w;
        }
        s = s * scale + sM[t];
        const float mn = fmaxf(m, s);
        l = l * __expf(m - mn) + __expf(s - mn);
        m = mn;
    }
    float ov[32];
    #pragma unroll
    for (int e = 0; e < 32; e++) ov[e] = 0.f;
    for (int t = 0; t < NTXT; t++) {
        const float* kr = &sKf[t * HD];
        float s = 0.f;
        #pragma unroll
        for (int d4 = 0; d4 < 8; d4++) {
            const float4 k4 = *reinterpret_cast<const float4*>(kr + d4 * 4);
            s += q[d4*4+0]*k4.x + q[d4*4+1]*k4.y + q[d4*4+2]*k4.z + q[d4*4+3]*k4.w;
        }
        s = s * scale + sM[t];
        const float p = __expf(s - m);
        const unsigned short* vr = &sVb[t * HD];
        #pragma unroll
        for (int e8 = 0; e8 < 4; e8++) {
            s16x8 v8 = *reinterpret_cast<const s16x8*>(vr + e8 * 8);
            #pragma unroll
            for (int j = 0; j < 8; j++) ov[e8 * 8 + j] += p * b2f(v8[j]);
        }
    }
    const float rl = 1.0f / l;
    unsigned short* op = oc + ((size_t)b * NIMG + n) * D_MODEL + (size_t)h * HD;
    #pragma unroll
    for (int e8 = 0; e8 < 4; e8++) {
        s16x8 o8;
        #pragma unroll
        for (int j = 0; j < 8; j++) o8[j] = f2b(ov[e8 * 8 + j] * rl);
        *reinterpret_cast<s16x8*>(op + e8 * 8) = o8;
    }
}

static inline int cdiv(int a, int b) { return (a + b - 1) / b; }

extern "C" void kernel_launch(void* const* d_in, const int* in_sizes, int n_in,
                              void* d_out, int out_size, void* d_ws, size_t ws_size,
                              hipStream_t stream)
{
    (void)in_sizes; (void)n_in; (void)out_size; (void)ws_size;
    const float* x0    = (const float*)d_in[0];
    const float* enc   = (const float*)d_in[1];
    const float* msk   = (const float*)d_in[2];
    const int*   tst   = (const int*)d_in[3];
    const float* W_t   = (const float*)d_in[4];
    const float* b_t   = (const float*)d_in[5];
    const float* sst   = (const float*)d_in[6];
    const float* W_qkv = (const float*)d_in[7];
    const float* W_o   = (const float*)d_in[8];
    const float* W_q   = (const float*)d_in[9];
    const float* W_kv  = (const float*)d_in[10];
    const float* W_co  = (const float*)d_in[11];
    const float* W_ff1 = (const float*)d_in[12];
    const float* W_ff2 = (const float*)d_in[13];
    float* out = (float*)d_out;
    char* ws = (char*)d_ws;

    // workspace layout (bytes); total 61,491,200 (~58.6 MiB)
    const size_t O_MOD = 0;                    //    107,520 (2 x 13440 f32)
    const size_t O_WT  = 131072;               // 15,482,880 (max: qkv slice 3456x2240 bf16)
    const size_t O_A1  = 15616000;             //  9,175,040 (2048x2240 bf16)
    const size_t O_A2  = O_A1 + 9175040;       //  9,175,040   (A1+A2 reused as preBuf f32 18.35MB)
    const size_t O_UA  = O_A2 + 9175040;       // 27,525,120 (qkv 2048x6720 | q2 | act 2048x5632)
    const size_t O_KVC = O_UA + 16777216;      //  5,376,000 (overlay; dead before act reaches here)

    float* mod = (float*)(ws + O_MOD);
    unsigned short* wT    = (unsigned short*)(ws + O_WT);
    unsigned short* bufA1 = (unsigned short*)(ws + O_A1);
    unsigned short* bufA2 = (unsigned short*)(ws + O_A2);
    unsigned short* bufUA = (unsigned short*)(ws + O_UA);
    unsigned short* kvcB  = (unsigned short*)(ws + O_KVC);
    float* preBuf = (float*)(ws + O_A1);       // 2048x2240 f32 over A1+A2 (dead at step 13)

    // 1. modulation table
    tmod_kernel<<<dim3(cdiv(MOD6, 256), 2), 256, 0, stream>>>(tst, W_t, b_t, sst, mod);
    // 2. hmod = LN(x0)*(1+sc1)+sh1 -> bufA1
    ln_mod_kernel<<<2048, 256, 0, stream>>>(x0, mod, bufA1, 1, 0);
    // 3. qkv = hmod @ W_qkv (relu on q,k) -> bufUA (ldc 6720), two N=3360 slices (Npad 3456)
    transpose_cast_kernel<<<dim3(108, 70), 256, 0, stream>>>(W_qkv, wT, 2240, 0, 2240, 3360, 3456, 6720, 0);
    gemm_lds_kernel<<<dim3(16, 27), 256, 0, stream>>>(bufA1, wT, 2048, 3456, 2240, 2240,
        3360, 6720, 0, nullptr, bufUA, nullptr, nullptr, nullptr, nullptr, 0, NIMG, 3360);
    transpose_cast_kernel<<<dim3(108, 70), 256, 0, stream>>>(W_qkv, wT, 2240, 0, 2240, 3360, 3456, 6720, 3360);
    gemm_lds_kernel<<<dim3(16, 27), 256, 0, stream>>>(bufA1, wT, 2048, 3456, 2240, 2240,
        3360, 6720, 3360, nullptr, bufUA, nullptr, nullptr, nullptr, nullptr, 0, NIMG, 1120);
    // 4. linear attention -> bufA1
    linattn_kernel<<<140, 256, 0, stream>>>(bufUA, bufA1);
    // 5. x1 = x0 + g1*(o @ W_o) -> out (f32) + bufA2 (bf16)
    transpose_cast_kernel<<<dim3(72, 70), 256, 0, stream>>>(W_o, wT, 2240, 0, 2240, 2240, 2304, 2240, 0);
    gemm_lds_kernel<<<dim3(16, 18), 256, 0, stream>>>(bufA1, wT, 2048, 2304, 2240, 2240,
        2240, 2240, 0, out, bufA2, x0, nullptr, mod, nullptr, 2, NIMG, 0);
    // 6. q2 = x1 @ W_q -> bufUA
    transpose_cast_kernel<<<dim3(72, 70), 256, 0, stream>>>(W_q, wT, 2240, 0, 2240, 2240, 2304, 2240, 0);
    gemm_lds_kernel<<<dim3(16, 18), 256, 0, stream>>>(bufA2, wT, 2048, 2304, 2240, 2240,
        2240, 2240, 0, nullptr, bufUA, nullptr, nullptr, nullptr, nullptr, 0, NIMG, 0);
    // 7. kvc = enc @ W_kv -> kvcB (ldc 4480), two N=2240 slices, A from f32 (guarded kernel)
    transpose_cast_kernel<<<dim3(70, 70), 256, 0, stream>>>(W_kv, wT, 2240, 0, 2240, 2240, 2240, 4480, 0);
    gemm_kernel<<<dim3(5, 18), 256, 0, stream>>>(nullptr, enc, wT, 600, 2240, 2240,
        4480, 0, nullptr, kvcB, nullptr, nullptr, nullptr, 0, NTXT, 0);
    transpose_cast_kernel<<<dim3(70, 70), 256, 0, stream>>>(W_kv, wT, 2240, 0, 2240, 2240, 2240, 4480, 2240);
    gemm_kernel<<<dim3(5, 18), 256, 0, stream>>>(nullptr, enc, wT, 600, 2240, 2240,
        4480, 2240, nullptr, kvcB, nullptr, nullptr, nullptr, 0, NTXT, 0);
    // 8. cross attention -> bufA1
    crossattn_kernel<<<dim3(4, 140), 256, 0, stream>>>(bufUA, kvcB, msk, bufA1);
    // 9. x2 = x1 + o_c @ W_co -> out (in-place residual)
    transpose_cast_kernel<<<dim3(72, 70), 256, 0, stream>>>(W_co, wT, 2240, 0, 2240, 2240, 2304, 2240, 0);
    gemm_lds_kernel<<<dim3(16, 18), 256, 0, stream>>>(bufA1, wT, 2048, 2304, 2240, 2240,
        2240, 2240, 0, out, nullptr, out, nullptr, nullptr, nullptr, 0, NIMG, 0);
    // 10. f = LN(x2)*(1+sc2)+sh2 -> bufA2
    ln_mod_kernel<<<2048, 256, 0, stream>>>(out, mod, bufA2, 4, 3);
    // 11+12. act (bufUA, ldc 5632) = geglu(f @ W_ff1): 4 quarters N=2800 (Npad 2816);
    //        quarters 2,3 (g-half) fuse act = silu(a)*g in the epilogue.
    for (int qi = 0; qi < 4; qi++) {
        const int wcol = qi * 2800;               // weight-space col offset
        const int ocol = (qi & 1) * 2800;         // output col offset within act
        const unsigned short* ga = (qi >= 2) ? bufUA : nullptr;
        transpose_cast_kernel<<<dim3(88, 70), 256, 0, stream>>>(W_ff1, wT, 2240, 0, 2240, 2800, 2816, 11200, wcol);
        gemm_lds_kernel<<<dim3(16, 22), 256, 0, stream>>>(bufA2, wT, 2048, 2816, 2240, 2240,
            2800, 5632, ocol, nullptr, bufUA, nullptr, nullptr, nullptr, ga, 0, NIMG, 0);
    }
    // 13. x = x2 + g2*(act @ W_ff2) -> out; K=5600 split into two K=2816 halves (zero-padded),
    //     half 0 -> preBuf (f32), half 1 adds preBuf before gate, then resid.
    transpose_cast_kernel<<<dim3(72, 88), 256, 0, stream>>>(W_ff2, wT, 5600, 0, 2816, 2240, 2304, 2240, 0);
    gemm_lds_kernel<<<dim3(16, 18), 256, 0, stream>>>(bufUA, wT, 2048, 2304, 2816, 5632,
        2240, 2240, 0, preBuf, nullptr, nullptr, nullptr, nullptr, nullptr, 0, NIMG, 0);
    transpose_cast_kernel<<<dim3(72, 88), 256, 0, stream>>>(W_ff2, wT, 5600, 2816, 2816, 2240, 2304, 2240, 0);
    gemm_lds_kernel<<<dim3(16, 18), 256, 0, stream>>>(bufUA + 2816, wT, 2048, 2304, 2816, 5632,
        2240, 2240, 0, out, nullptr, out, preBuf, mod, nullptr, 5, NIMG, 0);
}